// Round 2
// baseline (250.720 us; speedup 1.0000x reference)
//
#include <hip/hip_runtime.h>
#include <math.h>

#define H 512
#define W 512
#define RM 8
#define TSX 32
#define TSY 8
#define LW (TSX + 2*RM)   // 48
#define LH (TSY + 2*RM)   // 24
#define PL (LH * LW)      // 1152 floats per plane

#if defined(__has_builtin) && __has_builtin(__builtin_amdgcn_exp2f)
#define EXP2(x) __builtin_amdgcn_exp2f(x)
#else
#define EXP2(x) exp2f(x)
#endif

__global__ __launch_bounds__(256) void bilateral_kernel(
    const float* __restrict__ img, const float* __restrict__ params,
    float* __restrict__ out)
{
    // SoA planes: r, g, b, q = A*(s.s)  -> conflict-free, merge-friendly reads
    __shared__ float lds[4 * PL];
    float* __restrict__ pr = lds;
    float* __restrict__ pg = lds + PL;
    float* __restrict__ pb = lds + 2 * PL;
    float* __restrict__ pq = lds + 3 * PL;

    const int n  = blockIdx.z;
    const int x0 = blockIdx.x * TSX;
    const int y0 = blockIdx.y * TSY;

    const float p0 = params[n*3 + 0];
    const float p1 = params[n*3 + 1];
    const float p2 = params[n*3 + 2];
    const int win = ((int)p0) * 14 + 3;     // window = int(p0)*7*2 + 3
    const int r   = (win - 1) >> 1;
    const float sc = fmaf(p1, 99.0f, 1.0f);
    const float ss = fmaf(p2, 99.0f, 1.0f);
    const float LOG2E = 1.4426950408889634f;
    // values kept at 0..1; 255^2 and log2(e) folded into A (A < 0)
    const float A  = -65025.0f * LOG2E / (2.0f * sc * sc);
    const float Bs = -LOG2E / (2.0f * ss * ss);

    // ---- stage tile + halo into 4 SoA planes; q = A*(s.s) precomputed ----
    const float* imgN = img + (size_t)n * (3 * H * W);
    for (int idx = threadIdx.x; idx < PL; idx += 256) {
        int ly = idx / LW;
        int lx = idx - ly * LW;
        int gy = y0 + ly - RM; gy = gy < 0 ? 0 : (gy > H-1 ? H-1 : gy);
        int gx = x0 + lx - RM; gx = gx < 0 ? 0 : (gx > W-1 ? W-1 : gx);
        int g = gy * W + gx;
        float vr = imgN[g];
        float vg = imgN[H*W + g];
        float vb = imgN[2*H*W + g];
        pr[idx] = vr;
        pg[idx] = vg;
        pb[idx] = vb;
        pq[idx] = A * fmaf(vr, vr, fmaf(vg, vg, vb * vb));
    }
    __syncthreads();

    const int tx = threadIdx.x & (TSX - 1);
    const int ty = threadIdx.x >> 5;

    const int cbase = (ty + RM) * LW + (tx + RM);
    const float cr = pr[cbase], cg = pg[cbase], cb = pb[cbase];
    const float K   = A * fmaf(cr, cr, fmaf(cg, cg, cb * cb)); // A*(c.c)
    const float cr2 = -2.0f * A * cr;
    const float cg2 = -2.0f * A * cg;
    const float cb2 = -2.0f * A * cb;

    // spatial-x bias + K folded; masked taps -> -inf -> exp2 = 0 exactly
    float bxK[2*RM + 1];
    #pragma unroll
    for (int i = 0; i <= 2*RM; ++i) {
        int d  = i - RM;
        int ad = d < 0 ? -d : d;
        bxK[i] = ((ad <= r) ? Bs * (float)(d*d) : -__builtin_inff()) + K;
    }

    float nr = 0.0f, ng = 0.0f, nb = 0.0f, nd = 0.0f;

    for (int dy = -RM; dy <= RM; ++dy) {
        int ady = dy < 0 ? -dy : dy;
        float by = (ady <= r) ? Bs * (float)(dy*dy) : -__builtin_inff();
        float wy = EXP2(by);                 // 0 for masked rows
        const int rb = (ty + RM + dy) * LW + tx;
        const float* __restrict__ lr = &pr[rb];
        const float* __restrict__ lg = &pg[rb];
        const float* __restrict__ lb = &pb[rb];
        const float* __restrict__ lq = &pq[rb];

        float rr = 0.0f, rg = 0.0f, rbv = 0.0f, rd = 0.0f;
        #pragma unroll
        for (int i = 0; i <= 2*RM; ++i) {
            float sr = lr[i];
            float sg = lg[i];
            float sb = lb[i];
            float sq = lq[i];
            // A*d2 + bx + K = sq + cr2*sr + cg2*sg + cb2*sb + bxK[i]
            float t = fmaf(cr2, sr, sq);
            t = fmaf(cg2, sg, t);
            t = fmaf(cb2, sb, t);
            float w = EXP2(t + bxK[i]);
            rr  = fmaf(w, sr, rr);
            rg  = fmaf(w, sg, rg);
            rbv = fmaf(w, sb, rbv);
            rd += w;
        }
        nr = fmaf(wy, rr,  nr);
        ng = fmaf(wy, rg,  ng);
        nb = fmaf(wy, rbv, nb);
        nd = fmaf(wy, rd,  nd);
    }

    const float inv = __builtin_amdgcn_rcpf(nd);
    const int o = (y0 + ty) * W + (x0 + tx);
    float* outN = out + (size_t)n * (3 * H * W);
    outN[o]         = nr * inv;
    outN[H*W + o]   = ng * inv;
    outN[2*H*W + o] = nb * inv;
}

extern "C" void kernel_launch(void* const* d_in, const int* in_sizes, int n_in,
                              void* d_out, int out_size, void* d_ws, size_t ws_size,
                              hipStream_t stream) {
    const float* img    = (const float*)d_in[0];
    const float* params = (const float*)d_in[1];
    float* out          = (float*)d_out;
    dim3 grid(W / TSX, H / TSY, 8);
    bilateral_kernel<<<grid, dim3(256), 0, stream>>>(img, params, out);
}